// Round 3
// baseline (206.616 us; speedup 1.0000x reference)
//
#include <hip/hip_runtime.h>
#include <hip/hip_bf16.h>

#define BB 2
#define TT 2048
#define CCH 1024
#define NHH 16
#define HDD 64
#define M_TOK (BB*TT)      // 4096
#define N_QKV (3*CCH)      // 3072

typedef __attribute__((ext_vector_type(8))) short bf16x8;
typedef __attribute__((ext_vector_type(4))) float f32x4;
typedef unsigned short u16;
typedef unsigned int u32;

__device__ __forceinline__ u16 f2bf(float f) {
    union { float f; u32 u; } v; v.f = f;
    u32 u = v.u;
    u32 r = (u + 0x7FFFu + ((u >> 16) & 1u)) >> 16;
    return (u16)r;
}

// pack hi16(a),hi16(b) -> u32 {b.hi<<16 | a.hi} with +0x8000 rounding
__device__ __forceinline__ u32 pk_bf16(float a, float b) {
    u32 ua = __float_as_uint(a) + 0x8000u;
    u32 ub = __float_as_uint(b) + 0x8000u;
    return __builtin_amdgcn_perm(ub, ua, 0x07060302u);
}

__device__ __forceinline__ void async_copy16(const void* g, void* l) {
    __builtin_amdgcn_global_load_lds((__attribute__((address_space(1))) void*)g,
                                     (__attribute__((address_space(3))) void*)l,
                                     16, 0, 0);
}

// ---------------- pre-pass kernels ----------------

__global__ __launch_bounds__(256) void cast_bf16_kernel(
    const float* __restrict__ src, u16* __restrict__ dst, int n4) {
    int i = blockIdx.x * 256 + threadIdx.x;
    if (i < n4) {
        float4 f = ((const float4*)src)[i];
        ushort4 o;
        o.x = f2bf(f.x); o.y = f2bf(f.y); o.z = f2bf(f.z); o.w = f2bf(f.w);
        ((ushort4*)dst)[i] = o;
    }
}

// src [R][Cn] fp32 -> dst [Cn][R] bf16; rows of dst with index < scale_rows get *= sc
__global__ __launch_bounds__(256) void transpose_bf16_kernel(
    const float* __restrict__ src, u16* __restrict__ dst, int R, int Cn,
    int scale_rows, float sc) {
    __shared__ float tile[32][33];
    int c0 = blockIdx.x * 32, r0 = blockIdx.y * 32;
    int tx = threadIdx.x, ty = threadIdx.y;
#pragma unroll
    for (int i = ty; i < 32; i += 8)
        tile[i][tx] = src[(size_t)(r0 + i) * Cn + c0 + tx];
    __syncthreads();
#pragma unroll
    for (int i = ty; i < 32; i += 8) {
        float v = tile[tx][i];
        if (c0 + i < scale_rows) v *= sc;
        dst[(size_t)(c0 + i) * R + r0 + tx] = f2bf(v);
    }
}

// ---------------- shared GEMM K-loop, BK=64, XOR-swizzled LDS ----------------

template<int SWAP, int NJ>
__device__ __forceinline__ void gemm_kloop64(
    const u16* __restrict__ A, const u16* __restrict__ Bt, int K,
    int m0, int n0, int t, u16* __restrict__ As, u16* __restrict__ Bs,
    f32x4 (&acc)[4][4])
{
    int lane = t & 63, w = t >> 6;
    int mw = (w >> 1) * 64, nw = (w & 1) * (NJ * 16);
    int mr = lane & 15, quad = lane >> 4;
    int lr = lane >> 3;                 // row-in-group 0..7
    int cswz = (lane & 7) ^ lr;         // swizzled 16B-chunk on the global side

    const u16* gA[4]; u16* lA[4];
#pragma unroll
    for (int p = 0; p < 4; ++p) {
        int grp = w * 4 + p;            // 16 groups x 8 rows = 128
        gA[p] = A + (size_t)(m0 + grp * 8 + lr) * K + cswz * 8;
        lA[p] = As + ((size_t)grp * 64 + lane) * 8;
    }
    const u16* gB[4]; u16* lB[4];
#pragma unroll
    for (int p = 0; p < NJ; ++p) {
        int grp = w * NJ + p;           // NJ groups per wave
        gB[p] = Bt + (size_t)(n0 + grp * 8 + lr) * K + cswz * 8;
        lB[p] = Bs + ((size_t)grp * 64 + lane) * 8;
    }

    int swm = mr & 7;
    for (int k0 = 0; k0 < K; k0 += 64) {
#pragma unroll
        for (int p = 0; p < 4; ++p) async_copy16(gA[p] + k0, lA[p]);
#pragma unroll
        for (int p = 0; p < NJ; ++p) async_copy16(gB[p] + k0, lB[p]);
        __syncthreads();
#pragma unroll
        for (int kk = 0; kk < 2; ++kk) {
            bf16x8 af[4], bfr[4];
#pragma unroll
            for (int i = 0; i < 4; ++i) {
                int r = mw + i * 16 + mr;
                af[i] = *(const bf16x8*)&As[r * 64 + (((kk * 4 + quad) ^ swm) << 3)];
            }
#pragma unroll
            for (int j = 0; j < NJ; ++j) {
                int r = nw + j * 16 + mr;
                bfr[j] = *(const bf16x8*)&Bs[r * 64 + (((kk * 4 + quad) ^ swm) << 3)];
            }
#pragma unroll
            for (int i = 0; i < 4; ++i)
#pragma unroll
                for (int j = 0; j < NJ; ++j) {
                    if (SWAP)
                        acc[i][j] = __builtin_amdgcn_mfma_f32_16x16x32_bf16(bfr[j], af[i], acc[i][j], 0, 0, 0);
                    else
                        acc[i][j] = __builtin_amdgcn_mfma_f32_16x16x32_bf16(af[i], bfr[j], acc[i][j], 0, 0, 0);
                }
        }
        __syncthreads();
    }
}

// ---------------- merged QKV GEMM: one 768-block dispatch ----------------

__global__ __launch_bounds__(256, 3) void qkv_gemm_kernel(
    const u16* __restrict__ A, const u16* __restrict__ Bt,
    u16* __restrict__ Qo, u16* __restrict__ Ko, u16* __restrict__ Vto)
{
    __shared__ u16 As[128 * 64];
    __shared__ u16 Bs[128 * 64];
    int t = threadIdx.x;
    int m0 = blockIdx.y * 128, n0 = blockIdx.x * 128;
    int part = n0 >> 10;
    int lane = t & 63, w = t >> 6;
    int mw = (w >> 1) * 64, nw = (w & 1) * 64;
    int mr = lane & 15, quad = lane >> 4;

    f32x4 zero = {0.f, 0.f, 0.f, 0.f};
    f32x4 acc[4][4];
#pragma unroll
    for (int i = 0; i < 4; ++i)
#pragma unroll
        for (int j = 0; j < 4; ++j) acc[i][j] = zero;

    if (part < 2) {   // block-uniform branch
        gemm_kloop64<1, 4>(A, Bt, CCH, m0, n0, t, As, Bs, acc);
        u16* dstp = part ? Ko : Qo;
#pragma unroll
        for (int i = 0; i < 4; ++i)
#pragma unroll
            for (int j = 0; j < 4; ++j) {
                int tok = m0 + mw + i * 16 + mr;
                int cg0 = n0 + nw + j * 16 + quad * 4;
                int cc = cg0 & 1023;
                int h = cc >> 6, d0 = cc & 63;
                int b = tok >> 11, tt = tok & 2047;
                int bh = b * NHH + h;
                uint2 o;
                o.x = pk_bf16(acc[i][j][0], acc[i][j][1]);
                o.y = pk_bf16(acc[i][j][2], acc[i][j][3]);
                *(uint2*)&dstp[((size_t)bh * TT + tt) * HDD + d0] = o;
            }
    } else {
        gemm_kloop64<0, 4>(A, Bt, CCH, m0, n0, t, As, Bs, acc);
#pragma unroll
        for (int i = 0; i < 4; ++i)
#pragma unroll
            for (int j = 0; j < 4; ++j) {
                int t0 = m0 + mw + i * 16 + quad * 4;
                int cg = n0 + nw + j * 16 + mr;
                int cc = cg & 1023;
                int h = cc >> 6, d = cc & 63;
                int b = t0 >> 11, tt0 = t0 & 2047;
                int bh = b * NHH + h;
                uint2 o;
                o.x = pk_bf16(acc[i][j][0], acc[i][j][1]);
                o.y = pk_bf16(acc[i][j][2], acc[i][j][3]);
                *(uint2*)&Vto[((size_t)bh * HDD + d) * TT + tt0] = o;
            }
    }
}

// ---------------- output projection: 128x64 tiles, 512 blocks (2/CU) ----------------

__global__ __launch_bounds__(256) void proj_gemm_kernel(
    const u16* __restrict__ A, const u16* __restrict__ Bt, float* __restrict__ Cout)
{
    __shared__ u16 As[128 * 64];
    __shared__ u16 Bs[64 * 64];
    int t = threadIdx.x;
    int m0 = blockIdx.y * 128, n0 = blockIdx.x * 64;
    int lane = t & 63, w = t >> 6;
    int mw = (w >> 1) * 64, nw = (w & 1) * 32;
    int mr = lane & 15, quad = lane >> 4;

    f32x4 zero = {0.f, 0.f, 0.f, 0.f};
    f32x4 acc[4][4];
#pragma unroll
    for (int i = 0; i < 4; ++i)
#pragma unroll
        for (int j = 0; j < 4; ++j) acc[i][j] = zero;

    gemm_kloop64<1, 2>(A, Bt, CCH, m0, n0, t, As, Bs, acc);

#pragma unroll
    for (int i = 0; i < 4; ++i)
#pragma unroll
        for (int j = 0; j < 2; ++j) {
            int tok = m0 + mw + i * 16 + mr;
            int cg0 = n0 + nw + j * 16 + quad * 4;
            float4 v;
            v.x = acc[i][j][0]; v.y = acc[i][j][1];
            v.z = acc[i][j][2]; v.w = acc[i][j][3];
            *(float4*)&Cout[(size_t)tok * CCH + cg0] = v;
        }
}

// ---------------- flash attention v13: 8-wave TLP ----------------
// v12 (kv-split) was NEUTRAL -> LDS BW is not the limit. Counters say
// latency-bound: MfmaUtil 14.5, VALUBusy 42, both pipes idle >50%, only
// 2 waves/SIMD resident (grid 512 x 256thr = 8 waves/CU).
// v13: 512-thread blocks, 8 waves = 4 q-slices(16 rows) x 2 kv-halves(32).
// Same grid 512 -> still 2 blocks/CU but 16 waves/CU = 4 waves/SIMD: twice
// the TLP to cover the frag-load -> MFMA -> exp2 -> P-LDS-roundtrip chain.
// Per-wave state halves (launch_bounds(512,4) pins VGPR<=128 - required!).
// A and B tiles get SEPARATE P buffers: removes the write-after-read
// serialization through the shared pb.

#define PST2 40   // P row stride (u16): 16B-aligned rows

template<bool MASK>
__device__ __forceinline__ void tile3(
    const bf16x8 (&kf)[2][2], const bf16x8 (&vf)[4], u16* __restrict__ pb,
    bf16x8 qf0, bf16x8 qf1, int m, int quad, int kvb, int qcol,
    f32x4 (&o)[4], f32x4& ls)
{
    f32x4 zero = {0.f, 0.f, 0.f, 0.f};
#pragma unroll
    for (int kc = 0; kc < 2; ++kc) {
        // S^T: kv = kvb + kc*16 + quad*4 + r (rows), q = qcol (cols)
        f32x4 s  = __builtin_amdgcn_mfma_f32_16x16x32_bf16(kf[kc][0], qf0, zero, 0, 0, 0);
        f32x4 st = __builtin_amdgcn_mfma_f32_16x16x32_bf16(kf[kc][1], qf1, s, 0, 0, 0);
        float e0, e1, e2, e3;
#pragma unroll
        for (int r = 0; r < 4; ++r) {
            float v = st[r];
            if (MASK && (kvb + kc * 16 + quad * 4 + r > qcol)) v = -1e30f;
            float e = __builtin_amdgcn_exp2f(v);
            ls[r] += e;
            if (r == 0) e0 = e; else if (r == 1) e1 = e; else if (r == 2) e2 = e; else e3 = e;
        }
        uint2 pk; pk.x = pk_bf16(e0, e1); pk.y = pk_bf16(e2, e3);
        *(uint2*)&pb[m * PST2 + kc * 16 + quad * 4] = pk;
    }
    // PV over this wave's 32-kv slice: one K=32 MFMA step
    bf16x8 pf = *(const bf16x8*)&pb[m * PST2 + quad * 8];
#pragma unroll
    for (int dg = 0; dg < 4; ++dg)
        o[dg] = __builtin_amdgcn_mfma_f32_16x16x32_bf16(vf[dg], pf, o[dg], 0, 0, 0);
}

// smem carve (u16 units): Ks dbuf [0,8192), Vs dbuf [8192,16384),
// P 8 waves x 2 tiles x 16*PST2 [16384,26624), l-exchange 128 f32 [26624,26880)
#define SM_U16 26880

__global__ __launch_bounds__(512, 4) void attn_kernel(
    const u16* __restrict__ Q, const u16* __restrict__ K,
    const u16* __restrict__ Vt, u16* __restrict__ Y)
{
    __shared__ __align__(16) u16 smem[SM_U16];
    int t = threadIdx.x;
    int w = t >> 6, lane = t & 63;
    int m = lane & 15, quad = lane >> 4;
    int iq = w >> 1, kh = w & 1;         // q-slice 0..3, kv-half 0..1

    int bid = blockIdx.x;
    int head = bid & 31;                 // head%8 = bid%8 -> XCD affinity
    int g = bid >> 5;                    // 0..15
    int pr = (g < 8) ? g : 23 - g;       // co-resident pair (bid, bid+256) sums const
    int qbA = pr;                        // light q-block (chunks 0..qbA)
    int qbB = 31 - pr;                   // heavy q-block (chunks 0..qbB)
    int rbA = qbA * 64 + iq * 16;
    int rbB = qbB * 64 + iq * 16;

    const u16* qpA = Q + ((size_t)head * TT + rbA + m) * HDD + quad * 8;
    const u16* qpB = Q + ((size_t)head * TT + rbB + m) * HDD + quad * 8;
    bf16x8 qA0 = *(const bf16x8*)qpA;
    bf16x8 qA1 = *(const bf16x8*)(qpA + 32);
    bf16x8 qB0 = *(const bf16x8*)qpB;
    bf16x8 qB1 = *(const bf16x8*)(qpB + 32);

    const u16* kbase = K + (size_t)head * TT * HDD;   // [t][d]
    const u16* vbase = Vt + (size_t)head * HDD * TT;  // [d][t]
    u16* pbA = smem + 16384 + (w * 2 + 0) * (16 * PST2);
    u16* pbB = smem + 16384 + (w * 2 + 1) * (16 * PST2);

    // staging geometry: each of 8 waves stages 8 K-rows + 8 V-rows
    int lr = lane >> 3;
    int cg = (lane & 7) ^ lr;            // XOR swizzle on global col-group
    int r0 = w * 8 + lr;                 // 0..63
    int loff = (w * 64 + lane) * 8;      // u16 offset within one 4096-u16 buffer

    f32x4 zero = {0.f, 0.f, 0.f, 0.f};
    f32x4 oA[4], oB[4], lsA = zero, lsB = zero;
#pragma unroll
    for (int dg = 0; dg < 4; ++dg) { oA[dg] = zero; oB[dg] = zero; }
    int qcA = rbA + m, qcB = rbB + m;
    int sw = m & 7;

    // prologue: stage chunk 0 into buffer 0
    async_copy16(kbase + (size_t)r0 * 64 + cg * 8, smem + loff);
    async_copy16(vbase + (size_t)r0 * TT + cg * 8, smem + 8192 + loff);

    for (int ic = 0; ic <= qbB; ++ic) {
        int buf = ic & 1;
        int kv0 = ic << 6;
        __syncthreads();            // chunk ic arrived; prev compute done
        if (ic < qbB) {             // prefetch chunk ic+1 into the other buffer
            int nkv = kv0 + 64;
            u16* dK = smem + (buf ^ 1) * 4096;
            u16* dV = smem + 8192 + (buf ^ 1) * 4096;
            async_copy16(kbase + (size_t)(nkv + r0) * 64 + cg * 8, dK + loff);
            async_copy16(vbase + (size_t)r0 * TT + nkv + cg * 8, dV + loff);
        }
        const u16* Kb = smem + buf * 4096;
        const u16* Vb = smem + 8192 + buf * 4096;
        // per-wave fragments: this wave's 32-kv half of K, matching V k-slice
        bf16x8 kf[2][2], vf[4];
#pragma unroll
        for (int kc = 0; kc < 2; ++kc) {
            int rr = kh * 32 + kc * 16 + m;
            kf[kc][0] = *(const bf16x8*)&Kb[rr * 64 + ((quad ^ sw) << 3)];
            kf[kc][1] = *(const bf16x8*)&Kb[rr * 64 + (((quad + 4) ^ sw) << 3)];
        }
#pragma unroll
        for (int dg = 0; dg < 4; ++dg) {
            int rr = dg * 16 + m;
            vf[dg] = *(const bf16x8*)&Vb[rr * 64 + (((kh * 4 + quad) ^ sw) << 3)];
        }
        int kvb = kv0 + kh * 32;
        if (ic < qbA)
            tile3<false>(kf, vf, pbA, qA0, qA1, m, quad, kvb, qcA, oA, lsA);
        else if (ic == qbA)
            tile3<true >(kf, vf, pbA, qA0, qA1, m, quad, kvb, qcA, oA, lsA);
        if (ic < qbB)
            tile3<false>(kf, vf, pbB, qB0, qB1, m, quad, kvb, qcB, oB, lsB);
        else
            tile3<true >(kf, vf, pbB, qB0, qB1, m, quad, kvb, qcB, oB, lsB);
    }

    // per-wave row-sums (partial over this wave's kv half)
    float lA = (lsA[0] + lsA[1]) + (lsA[2] + lsA[3]);
    float lB = (lsB[0] + lsB[1]) + (lsB[2] + lsB[3]);
    lA += __shfl_xor(lA, 16, 64); lA += __shfl_xor(lA, 32, 64);
    lB += __shfl_xor(lB, 16, 64); lB += __shfl_xor(lB, 32, 64);

    // cross-kh combine: kh=1 writes O-partials + l, kh=0 merges & stores
    __syncthreads();
    f32x4* ob = (f32x4*)smem;                 // 32KB overlay on K+V dbuf
    float* lb = (float*)&smem[26624];         // 128 floats
    if (kh) {
        f32x4* dst = ob + (size_t)iq * 512 + lane;
#pragma unroll
        for (int dg = 0; dg < 4; ++dg) {
            dst[dg * 64] = oA[dg];
            dst[(4 + dg) * 64] = oB[dg];
        }
        if (quad == 0) {
            lb[(iq * 2 + 0) * 16 + m] = lA;
            lb[(iq * 2 + 1) * 16 + m] = lB;
        }
    }
    __syncthreads();
    if (!kh) {
        f32x4* src = ob + (size_t)iq * 512 + lane;
#pragma unroll
        for (int dg = 0; dg < 4; ++dg) {
            oA[dg] += src[dg * 64];
            oB[dg] += src[(4 + dg) * 64];
        }
        lA += lb[(iq * 2 + 0) * 16 + m];
        lB += lb[(iq * 2 + 1) * 16 + m];
        float invA = 1.0f / lA, invB = 1.0f / lB;

        int b = head >> 4, h = head & 15;
        size_t roA = ((size_t)(b * TT + rbA + m)) * CCH + h * HDD;
        size_t roB = ((size_t)(b * TT + rbB + m)) * CCH + h * HDD;
#pragma unroll
        for (int dg = 0; dg < 4; ++dg) {
            uint2 ov;
            ov.x = pk_bf16(oA[dg][0] * invA, oA[dg][1] * invA);
            ov.y = pk_bf16(oA[dg][2] * invA, oA[dg][3] * invA);
            *(uint2*)&Y[roA + dg * 16 + quad * 4] = ov;
            ov.x = pk_bf16(oB[dg][0] * invB, oB[dg][1] * invB);
            ov.y = pk_bf16(oB[dg][2] * invB, oB[dg][3] * invB);
            *(uint2*)&Y[roB + dg * 16 + quad * 4] = ov;
        }
    }
}

// ---------------- launch ----------------

extern "C" void kernel_launch(void* const* d_in, const int* in_sizes, int n_in,
                              void* d_out, int out_size, void* d_ws, size_t ws_size,
                              hipStream_t stream) {
    const float* x      = (const float*)d_in[0];
    const float* w_attn = (const float*)d_in[1];
    const float* w_proj = (const float*)d_in[2];
    float* out = (float*)d_out;

    char* ws = (char*)d_ws;
    u16* x_bf   = (u16*)ws; ws += (size_t)M_TOK * CCH * 2;         // 8 MB
    u16* wqkvT  = (u16*)ws; ws += (size_t)N_QKV * CCH * 2;         // 6 MB
    u16* wprojT = (u16*)ws; ws += (size_t)CCH * CCH * 2;           // 2 MB
    u16* qbuf   = (u16*)ws; ws += (size_t)BB * NHH * TT * HDD * 2; // 8 MB
    u16* kbuf   = (u16*)ws; ws += (size_t)BB * NHH * TT * HDD * 2; // 8 MB
    u16* vtb    = (u16*)ws; ws += (size_t)BB * NHH * HDD * TT * 2; // 8 MB
    u16* yb     = (u16*)ws; ws += (size_t)M_TOK * CCH * 2;         // 8 MB

    // softmax scale * log2(e), folded into Q columns of w_attn during transpose
    const float QSC = 0.125f * 1.44269504088896f;

    // 1. cast x -> bf16
    cast_bf16_kernel<<<dim3(M_TOK * CCH / 4 / 256), dim3(256), 0, stream>>>(x, x_bf, M_TOK * CCH / 4);
    // 2. transpose weights -> bf16 [N][K]
    transpose_bf16_kernel<<<dim3(N_QKV / 32, CCH / 32), dim3(32, 8), 0, stream>>>(
        w_attn, wqkvT, CCH, N_QKV, CCH, QSC);
    transpose_bf16_kernel<<<dim3(CCH / 32, CCH / 32), dim3(32, 8), 0, stream>>>(
        w_proj, wprojT, CCH, CCH, 0, 1.0f);
    // 3. merged QKV GEMM: 768 blocks (3/CU), BK=64, swizzled LDS
    qkv_gemm_kernel<<<dim3(24, 32), dim3(256), 0, stream>>>(
        x_bf, wqkvT, qbuf, kbuf, vtb);
    // 4. flash attention v13 (512-thr blocks: 4 waves/SIMD TLP; split P buffers)
    attn_kernel<<<dim3(512), dim3(512), 0, stream>>>(qbuf, kbuf, vtb, yb);
    // 5. output projection: 128x64 tiles, BK=64, 512 blocks (2/CU)
    proj_gemm_kernel<<<dim3(16, 32), dim3(256), 0, stream>>>(yb, wprojT, out);
}

// Round 4
// 170.934 us; speedup vs baseline: 1.2087x; 1.2087x over previous
//
#include <hip/hip_runtime.h>
#include <hip/hip_bf16.h>

#define BB 2
#define TT 2048
#define CCH 1024
#define NHH 16
#define HDD 64
#define M_TOK (BB*TT)      // 4096
#define N_QKV (3*CCH)      // 3072

typedef __attribute__((ext_vector_type(8))) short bf16x8;
typedef __attribute__((ext_vector_type(4))) float f32x4;
typedef unsigned short u16;
typedef unsigned int u32;

__device__ __forceinline__ u16 f2bf(float f) {
    union { float f; u32 u; } v; v.f = f;
    u32 u = v.u;
    u32 r = (u + 0x7FFFu + ((u >> 16) & 1u)) >> 16;
    return (u16)r;
}

// pack hi16(a),hi16(b) -> u32 {b.hi<<16 | a.hi} with +0x8000 rounding
__device__ __forceinline__ u32 pk_bf16(float a, float b) {
    u32 ua = __float_as_uint(a) + 0x8000u;
    u32 ub = __float_as_uint(b) + 0x8000u;
    return __builtin_amdgcn_perm(ub, ua, 0x07060302u);
}

__device__ __forceinline__ void async_copy16(const void* g, void* l) {
    __builtin_amdgcn_global_load_lds((__attribute__((address_space(1))) void*)g,
                                     (__attribute__((address_space(3))) void*)l,
                                     16, 0, 0);
}

// ---------------- pre-pass kernels ----------------

__global__ __launch_bounds__(256) void cast_bf16_kernel(
    const float* __restrict__ src, u16* __restrict__ dst, int n4) {
    int i = blockIdx.x * 256 + threadIdx.x;
    if (i < n4) {
        float4 f = ((const float4*)src)[i];
        ushort4 o;
        o.x = f2bf(f.x); o.y = f2bf(f.y); o.z = f2bf(f.z); o.w = f2bf(f.w);
        ((ushort4*)dst)[i] = o;
    }
}

// src [R][Cn] fp32 -> dst [Cn][R] bf16; rows of dst with index < scale_rows get *= sc
__global__ __launch_bounds__(256) void transpose_bf16_kernel(
    const float* __restrict__ src, u16* __restrict__ dst, int R, int Cn,
    int scale_rows, float sc) {
    __shared__ float tile[32][33];
    int c0 = blockIdx.x * 32, r0 = blockIdx.y * 32;
    int tx = threadIdx.x, ty = threadIdx.y;
#pragma unroll
    for (int i = ty; i < 32; i += 8)
        tile[i][tx] = src[(size_t)(r0 + i) * Cn + c0 + tx];
    __syncthreads();
#pragma unroll
    for (int i = ty; i < 32; i += 8) {
        float v = tile[tx][i];
        if (c0 + i < scale_rows) v *= sc;
        dst[(size_t)(c0 + i) * R + r0 + tx] = f2bf(v);
    }
}

// ---------------- shared GEMM K-loop, BK=64, XOR-swizzled LDS ----------------

template<int SWAP, int NJ>
__device__ __forceinline__ void gemm_kloop64(
    const u16* __restrict__ A, const u16* __restrict__ Bt, int K,
    int m0, int n0, int t, u16* __restrict__ As, u16* __restrict__ Bs,
    f32x4 (&acc)[4][4])
{
    int lane = t & 63, w = t >> 6;
    int mw = (w >> 1) * 64, nw = (w & 1) * (NJ * 16);
    int mr = lane & 15, quad = lane >> 4;
    int lr = lane >> 3;                 // row-in-group 0..7
    int cswz = (lane & 7) ^ lr;         // swizzled 16B-chunk on the global side

    const u16* gA[4]; u16* lA[4];
#pragma unroll
    for (int p = 0; p < 4; ++p) {
        int grp = w * 4 + p;            // 16 groups x 8 rows = 128
        gA[p] = A + (size_t)(m0 + grp * 8 + lr) * K + cswz * 8;
        lA[p] = As + ((size_t)grp * 64 + lane) * 8;
    }
    const u16* gB[4]; u16* lB[4];
#pragma unroll
    for (int p = 0; p < NJ; ++p) {
        int grp = w * NJ + p;           // NJ groups per wave
        gB[p] = Bt + (size_t)(n0 + grp * 8 + lr) * K + cswz * 8;
        lB[p] = Bs + ((size_t)grp * 64 + lane) * 8;
    }

    int swm = mr & 7;
    for (int k0 = 0; k0 < K; k0 += 64) {
#pragma unroll
        for (int p = 0; p < 4; ++p) async_copy16(gA[p] + k0, lA[p]);
#pragma unroll
        for (int p = 0; p < NJ; ++p) async_copy16(gB[p] + k0, lB[p]);
        __syncthreads();
#pragma unroll
        for (int kk = 0; kk < 2; ++kk) {
            bf16x8 af[4], bfr[4];
#pragma unroll
            for (int i = 0; i < 4; ++i) {
                int r = mw + i * 16 + mr;
                af[i] = *(const bf16x8*)&As[r * 64 + (((kk * 4 + quad) ^ swm) << 3)];
            }
#pragma unroll
            for (int j = 0; j < NJ; ++j) {
                int r = nw + j * 16 + mr;
                bfr[j] = *(const bf16x8*)&Bs[r * 64 + (((kk * 4 + quad) ^ swm) << 3)];
            }
#pragma unroll
            for (int i = 0; i < 4; ++i)
#pragma unroll
                for (int j = 0; j < NJ; ++j) {
                    if (SWAP)
                        acc[i][j] = __builtin_amdgcn_mfma_f32_16x16x32_bf16(bfr[j], af[i], acc[i][j], 0, 0, 0);
                    else
                        acc[i][j] = __builtin_amdgcn_mfma_f32_16x16x32_bf16(af[i], bfr[j], acc[i][j], 0, 0, 0);
                }
        }
        __syncthreads();
    }
}

// ---------------- merged QKV GEMM: one 768-block dispatch ----------------

__global__ __launch_bounds__(256, 3) void qkv_gemm_kernel(
    const u16* __restrict__ A, const u16* __restrict__ Bt,
    u16* __restrict__ Qo, u16* __restrict__ Ko, u16* __restrict__ Vto)
{
    __shared__ u16 As[128 * 64];
    __shared__ u16 Bs[128 * 64];
    int t = threadIdx.x;
    int m0 = blockIdx.y * 128, n0 = blockIdx.x * 128;
    int part = n0 >> 10;
    int lane = t & 63, w = t >> 6;
    int mw = (w >> 1) * 64, nw = (w & 1) * 64;
    int mr = lane & 15, quad = lane >> 4;

    f32x4 zero = {0.f, 0.f, 0.f, 0.f};
    f32x4 acc[4][4];
#pragma unroll
    for (int i = 0; i < 4; ++i)
#pragma unroll
        for (int j = 0; j < 4; ++j) acc[i][j] = zero;

    if (part < 2) {   // block-uniform branch
        gemm_kloop64<1, 4>(A, Bt, CCH, m0, n0, t, As, Bs, acc);
        u16* dstp = part ? Ko : Qo;
#pragma unroll
        for (int i = 0; i < 4; ++i)
#pragma unroll
            for (int j = 0; j < 4; ++j) {
                int tok = m0 + mw + i * 16 + mr;
                int cg0 = n0 + nw + j * 16 + quad * 4;
                int cc = cg0 & 1023;
                int h = cc >> 6, d0 = cc & 63;
                int b = tok >> 11, tt = tok & 2047;
                int bh = b * NHH + h;
                uint2 o;
                o.x = pk_bf16(acc[i][j][0], acc[i][j][1]);
                o.y = pk_bf16(acc[i][j][2], acc[i][j][3]);
                *(uint2*)&dstp[((size_t)bh * TT + tt) * HDD + d0] = o;
            }
    } else {
        gemm_kloop64<0, 4>(A, Bt, CCH, m0, n0, t, As, Bs, acc);
#pragma unroll
        for (int i = 0; i < 4; ++i)
#pragma unroll
            for (int j = 0; j < 4; ++j) {
                int t0 = m0 + mw + i * 16 + quad * 4;
                int cg = n0 + nw + j * 16 + mr;
                int cc = cg & 1023;
                int h = cc >> 6, d = cc & 63;
                int b = t0 >> 11, tt0 = t0 & 2047;
                int bh = b * NHH + h;
                uint2 o;
                o.x = pk_bf16(acc[i][j][0], acc[i][j][1]);
                o.y = pk_bf16(acc[i][j][2], acc[i][j][3]);
                *(uint2*)&Vto[((size_t)bh * HDD + d) * TT + tt0] = o;
            }
    }
}

// ---------------- output projection: 128x64 tiles, 512 blocks (2/CU) ----------------

__global__ __launch_bounds__(256) void proj_gemm_kernel(
    const u16* __restrict__ A, const u16* __restrict__ Bt, float* __restrict__ Cout)
{
    __shared__ u16 As[128 * 64];
    __shared__ u16 Bs[64 * 64];
    int t = threadIdx.x;
    int m0 = blockIdx.y * 128, n0 = blockIdx.x * 64;
    int lane = t & 63, w = t >> 6;
    int mw = (w >> 1) * 64, nw = (w & 1) * 32;
    int mr = lane & 15, quad = lane >> 4;

    f32x4 zero = {0.f, 0.f, 0.f, 0.f};
    f32x4 acc[4][4];
#pragma unroll
    for (int i = 0; i < 4; ++i)
#pragma unroll
        for (int j = 0; j < 4; ++j) acc[i][j] = zero;

    gemm_kloop64<1, 2>(A, Bt, CCH, m0, n0, t, As, Bs, acc);

#pragma unroll
    for (int i = 0; i < 4; ++i)
#pragma unroll
        for (int j = 0; j < 2; ++j) {
            int tok = m0 + mw + i * 16 + mr;
            int cg0 = n0 + nw + j * 16 + quad * 4;
            float4 v;
            v.x = acc[i][j][0]; v.y = acc[i][j][1];
            v.z = acc[i][j][2]; v.w = acc[i][j][3];
            *(float4*)&Cout[(size_t)tok * CCH + cg0] = v;
        }
}

// ---------------- flash attention v14: 8-wave TLP, register-lean ----------------
// v13 proved the occupancy mechanism (16 waves/CU, Occupancy 16->35%) but
// launch_bounds(512,4) is CUDA-semantics min-BLOCKS/CU -> VGPR capped at 64
// -> accumulator spills (FETCH +12MB, WRITE +23MB scratch) -> 72us.
// v14: launch_bounds(512,2) -> cap 128 VGPR (2 blocks x 8 waves = 16 waves/CU),
// and fragment loads moved INLINE into tile3 (each frag used once; hoisted
// arrays were 32 VGPRs of dead live-range). Target: ~100 VGPR, zero spill.
// Tripwire: VGPR must be >64 and <=128; FETCH ~12.3MB, WRITE ~8.2MB.

#define PST2 40   // P row stride (u16): 16B-aligned rows

template<bool MASK>
__device__ __forceinline__ void tile3(
    const u16* __restrict__ Kb, const u16* __restrict__ Vb, u16* __restrict__ pb,
    bf16x8 qf0, bf16x8 qf1, int m, int quad, int sw, int kh, int kvb, int qcol,
    f32x4 (&o)[4], f32x4& ls)
{
    f32x4 zero = {0.f, 0.f, 0.f, 0.f};
#pragma unroll
    for (int kc = 0; kc < 2; ++kc) {
        int rr = kh * 32 + kc * 16 + m;
        bf16x8 kf0 = *(const bf16x8*)&Kb[rr * 64 + ((quad ^ sw) << 3)];
        bf16x8 kf1 = *(const bf16x8*)&Kb[rr * 64 + (((quad + 4) ^ sw) << 3)];
        // S^T: kv = kvb + kc*16 + quad*4 + r (rows), q = qcol (cols)
        f32x4 s  = __builtin_amdgcn_mfma_f32_16x16x32_bf16(kf0, qf0, zero, 0, 0, 0);
        f32x4 st = __builtin_amdgcn_mfma_f32_16x16x32_bf16(kf1, qf1, s, 0, 0, 0);
        float e0, e1, e2, e3;
#pragma unroll
        for (int r = 0; r < 4; ++r) {
            float v = st[r];
            if (MASK && (kvb + kc * 16 + quad * 4 + r > qcol)) v = -1e30f;
            float e = __builtin_amdgcn_exp2f(v);
            ls[r] += e;
            if (r == 0) e0 = e; else if (r == 1) e1 = e; else if (r == 2) e2 = e; else e3 = e;
        }
        uint2 pk; pk.x = pk_bf16(e0, e1); pk.y = pk_bf16(e2, e3);
        *(uint2*)&pb[m * PST2 + kc * 16 + quad * 4] = pk;
    }
    // PV over this wave's 32-kv slice: one K=32 MFMA step, V frags inline
    bf16x8 pf = *(const bf16x8*)&pb[m * PST2 + quad * 8];
#pragma unroll
    for (int dg = 0; dg < 4; ++dg) {
        int rr = dg * 16 + m;
        bf16x8 vf = *(const bf16x8*)&Vb[rr * 64 + (((kh * 4 + quad) ^ sw) << 3)];
        o[dg] = __builtin_amdgcn_mfma_f32_16x16x32_bf16(vf, pf, o[dg], 0, 0, 0);
    }
}

// smem carve (u16 units): Ks dbuf [0,8192), Vs dbuf [8192,16384),
// P 8 waves x 2 tiles x 16*PST2 [16384,26624), l-exchange 128 f32 [26624,26880)
#define SM_U16 26880

__global__ __launch_bounds__(512, 2) void attn_kernel(
    const u16* __restrict__ Q, const u16* __restrict__ K,
    const u16* __restrict__ Vt, u16* __restrict__ Y)
{
    __shared__ __align__(16) u16 smem[SM_U16];
    int t = threadIdx.x;
    int w = t >> 6, lane = t & 63;
    int m = lane & 15, quad = lane >> 4;
    int iq = w >> 1, kh = w & 1;         // q-slice 0..3, kv-half 0..1

    int bid = blockIdx.x;
    int head = bid & 31;                 // head%8 = bid%8 -> XCD affinity
    int g = bid >> 5;                    // 0..15
    int pr = (g < 8) ? g : 23 - g;       // co-resident pair (bid, bid+256) sums const
    int qbA = pr;                        // light q-block (chunks 0..qbA)
    int qbB = 31 - pr;                   // heavy q-block (chunks 0..qbB)
    int rbA = qbA * 64 + iq * 16;
    int rbB = qbB * 64 + iq * 16;

    const u16* qpA = Q + ((size_t)head * TT + rbA + m) * HDD + quad * 8;
    const u16* qpB = Q + ((size_t)head * TT + rbB + m) * HDD + quad * 8;
    bf16x8 qA0 = *(const bf16x8*)qpA;
    bf16x8 qA1 = *(const bf16x8*)(qpA + 32);
    bf16x8 qB0 = *(const bf16x8*)qpB;
    bf16x8 qB1 = *(const bf16x8*)(qpB + 32);

    const u16* kbase = K + (size_t)head * TT * HDD;   // [t][d]
    const u16* vbase = Vt + (size_t)head * HDD * TT;  // [d][t]
    u16* pbA = smem + 16384 + (w * 2 + 0) * (16 * PST2);
    u16* pbB = smem + 16384 + (w * 2 + 1) * (16 * PST2);

    // staging geometry: each of 8 waves stages 8 K-rows + 8 V-rows
    int lr = lane >> 3;
    int cg = (lane & 7) ^ lr;            // XOR swizzle on global col-group
    int r0 = w * 8 + lr;                 // 0..63
    int loff = (w * 64 + lane) * 8;      // u16 offset within one 4096-u16 buffer

    f32x4 zero = {0.f, 0.f, 0.f, 0.f};
    f32x4 oA[4], oB[4], lsA = zero, lsB = zero;
#pragma unroll
    for (int dg = 0; dg < 4; ++dg) { oA[dg] = zero; oB[dg] = zero; }
    int qcA = rbA + m, qcB = rbB + m;
    int sw = m & 7;

    // prologue: stage chunk 0 into buffer 0
    async_copy16(kbase + (size_t)r0 * 64 + cg * 8, smem + loff);
    async_copy16(vbase + (size_t)r0 * TT + cg * 8, smem + 8192 + loff);

    for (int ic = 0; ic <= qbB; ++ic) {
        int buf = ic & 1;
        int kv0 = ic << 6;
        __syncthreads();            // chunk ic arrived; prev compute done
        if (ic < qbB) {             // prefetch chunk ic+1 into the other buffer
            int nkv = kv0 + 64;
            u16* dK = smem + (buf ^ 1) * 4096;
            u16* dV = smem + 8192 + (buf ^ 1) * 4096;
            async_copy16(kbase + (size_t)(nkv + r0) * 64 + cg * 8, dK + loff);
            async_copy16(vbase + (size_t)r0 * TT + nkv + cg * 8, dV + loff);
        }
        const u16* Kb = smem + buf * 4096;
        const u16* Vb = smem + 8192 + buf * 4096;
        int kvb = kv0 + kh * 32;
        if (ic < qbA)
            tile3<false>(Kb, Vb, pbA, qA0, qA1, m, quad, sw, kh, kvb, qcA, oA, lsA);
        else if (ic == qbA)
            tile3<true >(Kb, Vb, pbA, qA0, qA1, m, quad, sw, kh, kvb, qcA, oA, lsA);
        if (ic < qbB)
            tile3<false>(Kb, Vb, pbB, qB0, qB1, m, quad, sw, kh, kvb, qcB, oB, lsB);
        else
            tile3<true >(Kb, Vb, pbB, qB0, qB1, m, quad, sw, kh, kvb, qcB, oB, lsB);
    }

    // per-wave row-sums (partial over this wave's kv half)
    float lA = (lsA[0] + lsA[1]) + (lsA[2] + lsA[3]);
    float lB = (lsB[0] + lsB[1]) + (lsB[2] + lsB[3]);
    lA += __shfl_xor(lA, 16, 64); lA += __shfl_xor(lA, 32, 64);
    lB += __shfl_xor(lB, 16, 64); lB += __shfl_xor(lB, 32, 64);

    // cross-kh combine: kh=1 writes O-partials + l, kh=0 merges & stores
    __syncthreads();
    f32x4* ob = (f32x4*)smem;                 // 32KB overlay on K+V dbuf
    float* lb = (float*)&smem[26624];         // 128 floats
    if (kh) {
        f32x4* dst = ob + (size_t)iq * 512 + lane;
#pragma unroll
        for (int dg = 0; dg < 4; ++dg) {
            dst[dg * 64] = oA[dg];
            dst[(4 + dg) * 64] = oB[dg];
        }
        if (quad == 0) {
            lb[(iq * 2 + 0) * 16 + m] = lA;
            lb[(iq * 2 + 1) * 16 + m] = lB;
        }
    }
    __syncthreads();
    if (!kh) {
        f32x4* src = ob + (size_t)iq * 512 + lane;
#pragma unroll
        for (int dg = 0; dg < 4; ++dg) {
            oA[dg] += src[dg * 64];
            oB[dg] += src[(4 + dg) * 64];
        }
        lA += lb[(iq * 2 + 0) * 16 + m];
        lB += lb[(iq * 2 + 1) * 16 + m];
        float invA = 1.0f / lA, invB = 1.0f / lB;

        int b = head >> 4, h = head & 15;
        size_t roA = ((size_t)(b * TT + rbA + m)) * CCH + h * HDD;
        size_t roB = ((size_t)(b * TT + rbB + m)) * CCH + h * HDD;
#pragma unroll
        for (int dg = 0; dg < 4; ++dg) {
            uint2 ov;
            ov.x = pk_bf16(oA[dg][0] * invA, oA[dg][1] * invA);
            ov.y = pk_bf16(oA[dg][2] * invA, oA[dg][3] * invA);
            *(uint2*)&Y[roA + dg * 16 + quad * 4] = ov;
            ov.x = pk_bf16(oB[dg][0] * invB, oB[dg][1] * invB);
            ov.y = pk_bf16(oB[dg][2] * invB, oB[dg][3] * invB);
            *(uint2*)&Y[roB + dg * 16 + quad * 4] = ov;
        }
    }
}

// ---------------- launch ----------------

extern "C" void kernel_launch(void* const* d_in, const int* in_sizes, int n_in,
                              void* d_out, int out_size, void* d_ws, size_t ws_size,
                              hipStream_t stream) {
    const float* x      = (const float*)d_in[0];
    const float* w_attn = (const float*)d_in[1];
    const float* w_proj = (const float*)d_in[2];
    float* out = (float*)d_out;

    char* ws = (char*)d_ws;
    u16* x_bf   = (u16*)ws; ws += (size_t)M_TOK * CCH * 2;         // 8 MB
    u16* wqkvT  = (u16*)ws; ws += (size_t)N_QKV * CCH * 2;         // 6 MB
    u16* wprojT = (u16*)ws; ws += (size_t)CCH * CCH * 2;           // 2 MB
    u16* qbuf   = (u16*)ws; ws += (size_t)BB * NHH * TT * HDD * 2; // 8 MB
    u16* kbuf   = (u16*)ws; ws += (size_t)BB * NHH * TT * HDD * 2; // 8 MB
    u16* vtb    = (u16*)ws; ws += (size_t)BB * NHH * HDD * TT * 2; // 8 MB
    u16* yb     = (u16*)ws; ws += (size_t)M_TOK * CCH * 2;         // 8 MB

    // softmax scale * log2(e), folded into Q columns of w_attn during transpose
    const float QSC = 0.125f * 1.44269504088896f;

    // 1. cast x -> bf16
    cast_bf16_kernel<<<dim3(M_TOK * CCH / 4 / 256), dim3(256), 0, stream>>>(x, x_bf, M_TOK * CCH / 4);
    // 2. transpose weights -> bf16 [N][K]
    transpose_bf16_kernel<<<dim3(N_QKV / 32, CCH / 32), dim3(32, 8), 0, stream>>>(
        w_attn, wqkvT, CCH, N_QKV, CCH, QSC);
    transpose_bf16_kernel<<<dim3(CCH / 32, CCH / 32), dim3(32, 8), 0, stream>>>(
        w_proj, wprojT, CCH, CCH, 0, 1.0f);
    // 3. merged QKV GEMM: 768 blocks (3/CU), BK=64, swizzled LDS
    qkv_gemm_kernel<<<dim3(24, 32), dim3(256), 0, stream>>>(
        x_bf, wqkvT, qbuf, kbuf, vtb);
    // 4. flash attention v14 (16 waves/CU, VGPR cap 128, no spill)
    attn_kernel<<<dim3(512), dim3(512), 0, stream>>>(qbuf, kbuf, vtb, yb);
    // 5. output projection: 128x64 tiles, BK=64, 512 blocks (2/CU)
    proj_gemm_kernel<<<dim3(16, 32), dim3(256), 0, stream>>>(yb, wprojT, out);
}